// Round 13
// baseline (141.675 us; speedup 1.0000x reference)
//
#include <hip/hip_runtime.h>
#include <hip/hip_bf16.h>

#define N_F 100
#define N_B 4096
#define DH 96
#define DT 192
#define BMR 32     // b-rows per block
#define NFB 4      // consecutive f per block (one per wave)
#define SROW 772   // stage row stride in floats (4*192 + 4)

// LDS-only barrier: does NOT drain vmcnt/expcnt -> in-flight global stores
// keep streaming across sync points (unlike __syncthreads()).
#define SYNC_LDS() asm volatile("s_waitcnt lgkmcnt(0)\n\ts_barrier" ::: "memory")

typedef unsigned short u16;
typedef unsigned int u32;
typedef __bf16 bf16x8 __attribute__((ext_vector_type(8)));
typedef float f32x4 __attribute__((ext_vector_type(4)));

union FragAB { bf16x8 v; uint2 q2[2]; uint4 q4; };

static __device__ __forceinline__ u16 f2bf(float v) {
    u32 b = __float_as_uint(v);
    return (u16)((b + 0x7FFFu + ((b >> 16) & 1u)) >> 16);  // RNE, no NaN in data
}

// tanh-form gelu: max abs deviation from exact erf-gelu ~3e-4 (<< bf16 rounding of h)
static __device__ __forceinline__ float gelu_fast(float p) {
    float p3 = p * p * p;
    float y  = fmaf(0.044715f, p3, p);
    float t  = exp2f(2.3022083f * y);
    float r  = __builtin_amdgcn_rcpf(1.0f + t);
    return fmaf(-p, r, p);                     // p - p/(1+t)
}

// W2[f][k][d] (f32) -> MFMA-fragment-ordered bf16 W2F.
// W2F[((ks*12 + DT16)*64 + q*16 + m)*8 + e]
//   d = DT16*16 + m ; k = ks*32 + (e>>2)*16 + q*4 + (e&3)
__global__ void convert_w2_kernel(const float* __restrict__ W2, u16* __restrict__ W2F) {
    int idx = blockIdx.x * 256 + threadIdx.x;          // over N_F*DH*(DT/4)
    if (idx >= N_F * DH * (DT / 4)) return;
    int f  = idx / (DH * (DT / 4));
    int r  = idx - f * (DH * (DT / 4));
    int k  = r / (DT / 4);
    int d4 = (r - k * (DT / 4)) * 4;
    const float4 w = *(const float4*)&W2[(f * DH + k) * DT + d4];

    int ks = k >> 5;
    int kr = k & 31;
    int q  = (kr >> 2) & 3;
    int e  = ((kr >> 4) << 2) | (kr & 3);
    u16* base = W2F + (size_t)f * (DH * DT);
    int DT16 = d4 >> 4;
    int m    = d4 & 15;
    size_t i0 = ((size_t)(ks * 12 + DT16) * 64 + q * 16 + m) * 8 + e;
    base[i0]      = f2bf(w.x);
    base[i0 + 8]  = f2bf(w.y);
    base[i0 + 16] = f2bf(w.z);
    base[i0 + 24] = f2bf(w.w);
}

// Block = 32 b-rows x 4 consecutive f (wave w owns f = fg*4+w, all 32 rows,
// all 192 d; acc[12][2] = 96 VGPR initialized to b2). Epilogue: 4 phases of
// 8 rows through a 24.7KB block-wide stage -> 3KB-contiguous runs per b-row,
// stored as 1KB full-line NT wave-instructions. 4 blocks/CU, 16 waves.
template <bool USE_WS>
__global__ __launch_bounds__(256, 4) void mlp_tok_kernel(
    const float* __restrict__ x, const float* __restrict__ W1,
    const float* __restrict__ b1, const float* __restrict__ W2,
    const float* __restrict__ b2, const u16* __restrict__ W2F,
    float* __restrict__ out)
{
    const int fg  = blockIdx.x;            // f-group fastest: shared b-window
    const int b0  = blockIdx.y * BMR;
    const int tid = threadIdx.x;
    const int lane = tid & 63;
    const int wv   = tid >> 6;
    const int f    = fg * NFB + wv;        // this wave's feature
    const int q    = lane >> 4;
    const int m    = lane & 15;

    __shared__ float stage[8][SROW];       // 24.7 KB single-buffer 8-row slice

    // acc init = b2 (D row = d = 4q+reg within dt tile, col = b = m)
    f32x4 acc[12][2];
    #pragma unroll
    for (int dt = 0; dt < 12; ++dt) {
        const f32x4 bq = *(const f32x4*)&b2[f * DT + dt * 16 + q * 4];
        acc[dt][0] = bq;
        acc[dt][1] = bq;
    }

    const float xv0 = x[(size_t)(b0 + m) * N_F + f];
    const float xv1 = x[(size_t)(b0 + 16 + m) * N_F + f];

    const u16* __restrict__ w2ff = USE_WS ? (W2F + (size_t)f * (DH * DT)) : nullptr;

    #pragma unroll
    for (int ks = 0; ks < 3; ++ks) {
        // B-fragments: elem j<4 -> k0+j, j>=4 -> k0+16+j (k0 = ks*32 + q*4)
        FragAB hb[2];
        #pragma unroll
        for (int hh = 0; hh < 2; ++hh) {
            const int k0 = ks * 32 + hh * 16 + q * 4;
            const float4 w1v = *(const float4*)&W1[f * DH + k0];
            const float4 b1v = *(const float4*)&b1[f * DH + k0];
            #pragma unroll
            for (int bt = 0; bt < 2; ++bt) {
                const float xv = bt ? xv1 : xv0;
                float g0 = gelu_fast(fmaf(xv, w1v.x, b1v.x));
                float g1 = gelu_fast(fmaf(xv, w1v.y, b1v.y));
                float g2 = gelu_fast(fmaf(xv, w1v.z, b1v.z));
                float g3 = gelu_fast(fmaf(xv, w1v.w, b1v.w));
                uint2 pk;
                pk.x = (u32)f2bf(g0) | ((u32)f2bf(g1) << 16);
                pk.y = (u32)f2bf(g2) | ((u32)f2bf(g3) << 16);
                hb[bt].q2[hh] = pk;
            }
        }
        #pragma unroll
        for (int dt = 0; dt < 12; ++dt) {
            FragAB a;
            if constexpr (USE_WS) {
                a.q4 = *(const uint4*)&w2ff[((size_t)(ks * 12 + dt) * 64 + lane) * 8];
            } else {
                const int d = dt * 16 + m;
                u16 tmp[8];
                #pragma unroll
                for (int e = 0; e < 8; ++e) {
                    const int k = ks * 32 + (e >> 2) * 16 + q * 4 + (e & 3);
                    tmp[e] = f2bf(W2[((size_t)f * DH + k) * DT + d]);
                }
                a.q4 = make_uint4(
                    (u32)tmp[0] | ((u32)tmp[1] << 16), (u32)tmp[2] | ((u32)tmp[3] << 16),
                    (u32)tmp[4] | ((u32)tmp[5] << 16), (u32)tmp[6] | ((u32)tmp[7] << 16));
            }
            acc[dt][0] = __builtin_amdgcn_mfma_f32_16x16x32_bf16(a.v, hb[0].v, acc[dt][0], 0, 0, 0);
            acc[dt][1] = __builtin_amdgcn_mfma_f32_16x16x32_bf16(a.v, hb[1].v, acc[dt][1], 0, 0, 0);
        }
    }

    // ---- Epilogue: 4 phases x 8 rows. Phase p: rows b0+p*8..b0+p*8+7
    // (bt = p>>1, lanes with (m>>3) == (p&1) write their 12 f32x4).
    #pragma unroll
    for (int p = 0; p < 4; ++p) {
        if (p) SYNC_LDS();                 // protect stage[] reuse (LDS-only wait)
        const int bt = p >> 1;
        if ((m >> 3) == (p & 1)) {
            const int srow = m & 7;
            #pragma unroll
            for (int dt = 0; dt < 12; ++dt)
                *(f32x4*)&stage[srow][wv * DT + dt * 16 + q * 4] = acc[dt][bt];
        }
        SYNC_LDS();
        // 8 rows x 3KB contiguous (4f x 768B); each wave instr = 1KB full lines
        #pragma unroll
        for (int i = 0; i < 6; ++i) {
            const int idx = i * 256 + tid;       // 0..1535 float4 slots
            const int row = idx / 192;
            const int c4  = idx - row * 192;     // 0..191 (4f x 48)
            f32x4 v = *(const f32x4*)&stage[row][c4 * 4];
            __builtin_nontemporal_store(
                v, (f32x4*)&out[((size_t)(b0 + p * 8 + row) * N_F + fg * NFB) * DT + c4 * 4]);
        }
    }
}

extern "C" void kernel_launch(void* const* d_in, const int* in_sizes, int n_in,
                              void* d_out, int out_size, void* d_ws, size_t ws_size,
                              hipStream_t stream) {
    const float* x  = (const float*)d_in[0];
    const float* W1 = (const float*)d_in[1];
    const float* b1 = (const float*)d_in[2];
    const float* W2 = (const float*)d_in[3];
    const float* b2 = (const float*)d_in[4];
    float* out = (float*)d_out;

    const size_t w2f_bytes = (size_t)N_F * DT * DH * sizeof(u16);
    dim3 grid(N_F / NFB, N_B / BMR);   // f-group fastest-varying

    if (ws_size >= w2f_bytes) {
        u16* W2F = (u16*)d_ws;
        convert_w2_kernel<<<(N_F * DH * (DT / 4) + 255) / 256, 256, 0, stream>>>(W2, W2F);
        mlp_tok_kernel<true><<<grid, 256, 0, stream>>>(x, W1, b1, W2, b2, W2F, out);
    } else {
        mlp_tok_kernel<false><<<grid, 256, 0, stream>>>(x, W1, b1, W2, b2, nullptr, out);
    }
}

// Round 14
// 75.605 us; speedup vs baseline: 1.8739x; 1.8739x over previous
//
#include <hip/hip_runtime.h>
#include <hip/hip_bf16.h>

#define N_F 100
#define N_B 4096
#define DH 96
#define DT 192
#define BM 64
#define HPAD 100    // bf16 elems per LDS row (pad from 96; 200B stride, 8B-aligned)
#define SPAD 196    // stage row stride in floats (192 + 4)

// LDS-only barrier: does NOT drain vmcnt/expcnt, so in-flight global stores
// keep streaming across sync points (unlike __syncthreads()).
#define SYNC_LDS() asm volatile("s_waitcnt lgkmcnt(0)\n\ts_barrier" ::: "memory")

typedef unsigned short u16;
typedef unsigned int u32;
typedef __bf16 bf16x8 __attribute__((ext_vector_type(8)));
typedef float f32x4 __attribute__((ext_vector_type(4)));

union FragAB { bf16x8 v; uint2 q2[2]; uint4 q4; };

static __device__ __forceinline__ u16 f2bf(float v) {
    u32 b = __float_as_uint(v);
    return (u16)((b + 0x7FFFu + ((b >> 16) & 1u)) >> 16);  // RNE, no NaN in data
}

// tanh-form gelu: max abs deviation from exact erf-gelu ~3e-4 (<< bf16 rounding of h)
static __device__ __forceinline__ float gelu_fast(float p) {
    float p3 = p * p * p;
    float y  = fmaf(0.044715f, p3, p);
    float t  = exp2f(2.3022083f * y);
    float r  = __builtin_amdgcn_rcpf(1.0f + t);
    return fmaf(-p, r, p);                     // p - p/(1+t)
}

// W2[f][k][d] (f32) -> MFMA-fragment-ordered bf16 W2F.
// W2F[((ks*12 + DT16)*64 + q*16 + m)*8 + e]
//   d = DT16*16 + m ; k = ks*32 + (e>>2)*16 + q*4 + (e&3)
__global__ void convert_w2_kernel(const float* __restrict__ W2, u16* __restrict__ W2F) {
    int idx = blockIdx.x * 256 + threadIdx.x;          // over N_F*DH*(DT/4)
    if (idx >= N_F * DH * (DT / 4)) return;
    int f  = idx / (DH * (DT / 4));
    int r  = idx - f * (DH * (DT / 4));
    int k  = r / (DT / 4);
    int d4 = (r - k * (DT / 4)) * 4;
    const float4 w = *(const float4*)&W2[(f * DH + k) * DT + d4];

    int ks = k >> 5;
    int kr = k & 31;
    int q  = (kr >> 2) & 3;
    int e  = ((kr >> 4) << 2) | (kr & 3);
    u16* base = W2F + (size_t)f * (DH * DT);
    int DT16 = d4 >> 4;
    int m    = d4 & 15;
    size_t i0 = ((size_t)(ks * 12 + DT16) * 64 + q * 16 + m) * 8 + e;
    base[i0]      = f2bf(w.x);
    base[i0 + 8]  = f2bf(w.y);
    base[i0 + 16] = f2bf(w.z);
    base[i0 + 24] = f2bf(w.w);
}

template <bool USE_WS>
__global__ __launch_bounds__(256, 4) void mlp_tok_kernel(
    const float* __restrict__ x, const float* __restrict__ W1,
    const float* __restrict__ b1, const float* __restrict__ W2,
    const float* __restrict__ b2, const u16* __restrict__ W2F,
    float* __restrict__ out)
{
    const int f   = blockIdx.x;            // f fastest: concurrent blocks share b-window
    const int b0  = blockIdx.y * BM;
    const int tid = threadIdx.x;
    const int lane = tid & 63;
    const int wv   = tid >> 6;             // wave id 0..3 -> 48-wide d strip

    __shared__ float x_lds[BM];
    __shared__ u16 h_lds[BM][HPAD];
    __shared__ float stage[32][SPAD];      // epilogue staging, two 32-row halves
    __shared__ u16 w2t_lds[USE_WS ? 1 : DT][HPAD];

    if (tid < BM) x_lds[tid] = x[(size_t)(b0 + tid) * N_F + f];
    SYNC_LDS();

    // ---- Phase 1: h = gelu(x*W1 + b1) -> bf16 LDS [row=b][k] ----
    {
        const int row = tid & (BM - 1);
        const int kc  = (tid >> 6) * 24;
        const float xv = x_lds[row];
        #pragma unroll
        for (int c = 0; c < 6; ++c) {
            const int k = kc + c * 4;
            const float4 w1v = *(const float4*)&W1[f * DH + k];
            const float4 b1v = *(const float4*)&b1[f * DH + k];
            float g0 = gelu_fast(fmaf(xv, w1v.x, b1v.x));
            float g1 = gelu_fast(fmaf(xv, w1v.y, b1v.y));
            float g2 = gelu_fast(fmaf(xv, w1v.z, b1v.z));
            float g3 = gelu_fast(fmaf(xv, w1v.w, b1v.w));
            uint2 pk;
            pk.x = (u32)f2bf(g0) | ((u32)f2bf(g1) << 16);
            pk.y = (u32)f2bf(g2) | ((u32)f2bf(g3) << 16);
            *(uint2*)&h_lds[row][k] = pk;
        }
    }

    // ---- Fallback: stage W2[f] transposed into LDS as bf16 [d][k] ----
    if constexpr (!USE_WS) {
        #pragma unroll
        for (int i = 0; i < (DT * DH) / (256 * 4); ++i) {
            const int e = (i * 256 + tid) * 4;
            const int k = e / DT;
            const int n = e - k * DT;
            const float4 wv4 = *(const float4*)&W2[(f * DH + k) * DT + n];
            w2t_lds[n + 0][k] = f2bf(wv4.x);
            w2t_lds[n + 1][k] = f2bf(wv4.y);
            w2t_lds[n + 2][k] = f2bf(wv4.z);
            w2t_lds[n + 3][k] = f2bf(wv4.w);
        }
    }
    SYNC_LDS();

    // ---- Phase 2: swapped MFMA. A = W2 (rows=d), B = h^T (cols=b). ----
    const int q = lane >> 4;
    const int m = lane & 15;

    f32x4 acc[3][4];
    #pragma unroll
    for (int dt = 0; dt < 3; ++dt)
        #pragma unroll
        for (int bt = 0; bt < 4; ++bt)
            acc[dt][bt] = (f32x4){0.f, 0.f, 0.f, 0.f};

    const u16* __restrict__ w2ff = USE_WS ? (W2F + (size_t)f * (DH * DT)) : nullptr;

    #pragma unroll
    for (int ks = 0; ks < 3; ++ks) {
        const int k0 = ks * 32 + q * 4;
        FragAB a[3], hb[4];
        #pragma unroll
        for (int dt = 0; dt < 3; ++dt) {
            if constexpr (USE_WS) {
                a[dt].q4 = *(const uint4*)&w2ff[((ks * 12 + wv * 3 + dt) * 64 + lane) * 8];
            } else {
                const int d = wv * 48 + dt * 16 + m;
                a[dt].q2[0] = *(const uint2*)&w2t_lds[d][k0];
                a[dt].q2[1] = *(const uint2*)&w2t_lds[d][k0 + 16];
            }
        }
        #pragma unroll
        for (int bt = 0; bt < 4; ++bt) {
            hb[bt].q2[0] = *(const uint2*)&h_lds[bt * 16 + m][k0];
            hb[bt].q2[1] = *(const uint2*)&h_lds[bt * 16 + m][k0 + 16];
        }
        #pragma unroll
        for (int dt = 0; dt < 3; ++dt)
            #pragma unroll
            for (int bt = 0; bt < 4; ++bt)
                acc[dt][bt] = __builtin_amdgcn_mfma_f32_16x16x32_bf16(
                    a[dt].v, hb[bt].v, acc[dt][bt], 0, 0, 0);
    }

    // ---- Epilogue: LDS-staged transpose -> linear 1KB nontemporal wave stores.
    // acc D layout: row = d = 4q+reg (within dt tile), col = b = m.
    const int dbase = wv * 48;
    f32x4 b2q[3];
    #pragma unroll
    for (int dt = 0; dt < 3; ++dt)
        b2q[dt] = *(const f32x4*)&b2[f * DT + dbase + dt * 16 + q * 4];

    #pragma unroll
    for (int hh = 0; hh < 2; ++hh) {
        if (hh) SYNC_LDS();                // protect stage[] reuse (LDS-only wait)
        #pragma unroll
        for (int bt2 = 0; bt2 < 2; ++bt2) {
            const int bt = hh * 2 + bt2;
            #pragma unroll
            for (int dt = 0; dt < 3; ++dt) {
                f32x4 v = acc[dt][bt] + b2q[dt];
                *(f32x4*)&stage[bt2 * 16 + m][dbase + dt * 16 + q * 4] = v;
            }
        }
        SYNC_LDS();
        // store 32 rows x 768B; every wave instruction = 1KB of full 128B lines
        #pragma unroll
        for (int i = 0; i < 6; ++i) {
            const int idx = i * 256 + tid;       // 0..1535 float4 slots
            const int row = idx / 48;
            const int c4  = idx - row * 48;
            f32x4 v = *(const f32x4*)&stage[row][c4 * 4];
            __builtin_nontemporal_store(
                v, (f32x4*)&out[((size_t)(b0 + hh * 32 + row) * N_F + f) * DT + c4 * 4]);
        }
    }
}

extern "C" void kernel_launch(void* const* d_in, const int* in_sizes, int n_in,
                              void* d_out, int out_size, void* d_ws, size_t ws_size,
                              hipStream_t stream) {
    const float* x  = (const float*)d_in[0];
    const float* W1 = (const float*)d_in[1];
    const float* b1 = (const float*)d_in[2];
    const float* W2 = (const float*)d_in[3];
    const float* b2 = (const float*)d_in[4];
    float* out = (float*)d_out;

    const size_t w2f_bytes = (size_t)N_F * DT * DH * sizeof(u16);
    dim3 grid(N_F, N_B / BM);   // f fastest-varying

    if (ws_size >= w2f_bytes) {
        u16* W2F = (u16*)d_ws;
        convert_w2_kernel<<<(N_F * DH * (DT / 4) + 255) / 256, 256, 0, stream>>>(W2, W2F);
        mlp_tok_kernel<true><<<grid, 256, 0, stream>>>(x, W1, b1, W2, b2, W2F, out);
    } else {
        mlp_tok_kernel<false><<<grid, 256, 0, stream>>>(x, W1, b1, W2, b2, nullptr, out);
    }
}

// Round 15
// 72.507 us; speedup vs baseline: 1.9540x; 1.0427x over previous
//
#include <hip/hip_runtime.h>
#include <hip/hip_bf16.h>

#define N_F 100
#define N_B 4096
#define DH 96
#define DT 192
#define BM 32
#define HPAD 100    // bf16 elems per LDS row (pad from 96; 200B stride, 8B-aligned)
#define SPAD 196    // stage row stride in floats (192 + 4)

// LDS-only barrier: does NOT drain vmcnt/expcnt, so in-flight global stores
// keep streaming across sync points (unlike __syncthreads()).
#define SYNC_LDS() asm volatile("s_waitcnt lgkmcnt(0)\n\ts_barrier" ::: "memory")

typedef unsigned short u16;
typedef unsigned int u32;
typedef __bf16 bf16x8 __attribute__((ext_vector_type(8)));
typedef float f32x4 __attribute__((ext_vector_type(4)));

union FragAB { bf16x8 v; uint2 q2[2]; uint4 q4; };

static __device__ __forceinline__ u16 f2bf(float v) {
    u32 b = __float_as_uint(v);
    return (u16)((b + 0x7FFFu + ((b >> 16) & 1u)) >> 16);  // RNE, no NaN in data
}

// tanh-form gelu: max abs deviation from exact erf-gelu ~3e-4 (<< bf16 rounding of h)
static __device__ __forceinline__ float gelu_fast(float p) {
    float p3 = p * p * p;
    float y  = fmaf(0.044715f, p3, p);
    float t  = exp2f(2.3022083f * y);
    float r  = __builtin_amdgcn_rcpf(1.0f + t);
    return fmaf(-p, r, p);                     // p - p/(1+t)
}

// W2[f][k][d] (f32) -> MFMA-fragment-ordered bf16 W2F.
// W2F[((ks*12 + DT16)*64 + q*16 + m)*8 + e]
//   d = DT16*16 + m ; k = ks*32 + (e>>2)*16 + q*4 + (e&3)
__global__ void convert_w2_kernel(const float* __restrict__ W2, u16* __restrict__ W2F) {
    int idx = blockIdx.x * 256 + threadIdx.x;          // over N_F*DH*(DT/4)
    if (idx >= N_F * DH * (DT / 4)) return;
    int f  = idx / (DH * (DT / 4));
    int r  = idx - f * (DH * (DT / 4));
    int k  = r / (DT / 4);
    int d4 = (r - k * (DT / 4)) * 4;
    const float4 w = *(const float4*)&W2[(f * DH + k) * DT + d4];

    int ks = k >> 5;
    int kr = k & 31;
    int q  = (kr >> 2) & 3;
    int e  = ((kr >> 4) << 2) | (kr & 3);
    u16* base = W2F + (size_t)f * (DH * DT);
    int DT16 = d4 >> 4;
    int m    = d4 & 15;
    size_t i0 = ((size_t)(ks * 12 + DT16) * 64 + q * 16 + m) * 8 + e;
    base[i0]      = f2bf(w.x);
    base[i0 + 8]  = f2bf(w.y);
    base[i0 + 16] = f2bf(w.z);
    base[i0 + 24] = f2bf(w.w);
}

// R12 structure with BM=32: ~19KB LDS -> 6 blocks/CU (24 waves/CU) with
// __launch_bounds__(256,6) capping VGPR at ~85. Higher resident-block count
// diversifies epilogue phases -> better store-issue duty cycle.
template <bool USE_WS>
__global__ __launch_bounds__(256, 6) void mlp_tok_kernel(
    const float* __restrict__ x, const float* __restrict__ W1,
    const float* __restrict__ b1, const float* __restrict__ W2,
    const float* __restrict__ b2, const u16* __restrict__ W2F,
    float* __restrict__ out)
{
    const int f   = blockIdx.x;            // f fastest: concurrent blocks share b-window
    const int b0  = blockIdx.y * BM;
    const int tid = threadIdx.x;
    const int lane = tid & 63;
    const int wv   = tid >> 6;             // wave id 0..3 -> 48-wide d strip

    __shared__ float x_lds[BM];
    __shared__ u16 h_lds[BM][HPAD];
    __shared__ float stage[16][SPAD];      // epilogue staging, two 16-row halves
    __shared__ u16 w2t_lds[USE_WS ? 1 : DT][HPAD];

    if (tid < BM) x_lds[tid] = x[(size_t)(b0 + tid) * N_F + f];
    SYNC_LDS();

    // ---- Phase 1: h = gelu(x*W1 + b1) -> bf16 LDS [row=b][k] ----
    // 32 rows x 96 k = 3072 vals, 12/thread: row = tid&31, k-chunk = (tid>>5)*12
    {
        const int row = tid & (BM - 1);
        const int kc  = (tid >> 5) * 12;
        const float xv = x_lds[row];
        #pragma unroll
        for (int c = 0; c < 3; ++c) {
            const int k = kc + c * 4;
            const float4 w1v = *(const float4*)&W1[f * DH + k];
            const float4 b1v = *(const float4*)&b1[f * DH + k];
            float g0 = gelu_fast(fmaf(xv, w1v.x, b1v.x));
            float g1 = gelu_fast(fmaf(xv, w1v.y, b1v.y));
            float g2 = gelu_fast(fmaf(xv, w1v.z, b1v.z));
            float g3 = gelu_fast(fmaf(xv, w1v.w, b1v.w));
            uint2 pk;
            pk.x = (u32)f2bf(g0) | ((u32)f2bf(g1) << 16);
            pk.y = (u32)f2bf(g2) | ((u32)f2bf(g3) << 16);
            *(uint2*)&h_lds[row][k] = pk;
        }
    }

    // ---- Fallback: stage W2[f] transposed into LDS as bf16 [d][k] ----
    if constexpr (!USE_WS) {
        #pragma unroll
        for (int i = 0; i < (DT * DH) / (256 * 4); ++i) {
            const int e = (i * 256 + tid) * 4;
            const int k = e / DT;
            const int n = e - k * DT;
            const float4 wv4 = *(const float4*)&W2[(f * DH + k) * DT + n];
            w2t_lds[n + 0][k] = f2bf(wv4.x);
            w2t_lds[n + 1][k] = f2bf(wv4.y);
            w2t_lds[n + 2][k] = f2bf(wv4.z);
            w2t_lds[n + 3][k] = f2bf(wv4.w);
        }
    }
    SYNC_LDS();

    // ---- Phase 2: swapped MFMA. A = W2 (rows=d), B = h^T (cols=b). ----
    const int q = lane >> 4;
    const int m = lane & 15;

    f32x4 acc[3][2];
    #pragma unroll
    for (int dt = 0; dt < 3; ++dt)
        #pragma unroll
        for (int bt = 0; bt < 2; ++bt)
            acc[dt][bt] = (f32x4){0.f, 0.f, 0.f, 0.f};

    const u16* __restrict__ w2ff = USE_WS ? (W2F + (size_t)f * (DH * DT)) : nullptr;

    #pragma unroll
    for (int ks = 0; ks < 3; ++ks) {
        const int k0 = ks * 32 + q * 4;
        FragAB a[3], hb[2];
        #pragma unroll
        for (int dt = 0; dt < 3; ++dt) {
            if constexpr (USE_WS) {
                a[dt].q4 = *(const uint4*)&w2ff[((ks * 12 + wv * 3 + dt) * 64 + lane) * 8];
            } else {
                const int d = wv * 48 + dt * 16 + m;
                a[dt].q2[0] = *(const uint2*)&w2t_lds[d][k0];
                a[dt].q2[1] = *(const uint2*)&w2t_lds[d][k0 + 16];
            }
        }
        #pragma unroll
        for (int bt = 0; bt < 2; ++bt) {
            hb[bt].q2[0] = *(const uint2*)&h_lds[bt * 16 + m][k0];
            hb[bt].q2[1] = *(const uint2*)&h_lds[bt * 16 + m][k0 + 16];
        }
        #pragma unroll
        for (int dt = 0; dt < 3; ++dt)
            #pragma unroll
            for (int bt = 0; bt < 2; ++bt)
                acc[dt][bt] = __builtin_amdgcn_mfma_f32_16x16x32_bf16(
                    a[dt].v, hb[bt].v, acc[dt][bt], 0, 0, 0);
    }

    // ---- Epilogue: LDS-staged transpose -> linear 1KB nontemporal wave stores.
    // acc D layout: row = d = 4q+reg (within dt tile), col = b = m.
    const int dbase = wv * 48;
    f32x4 b2q[3];
    #pragma unroll
    for (int dt = 0; dt < 3; ++dt)
        b2q[dt] = *(const f32x4*)&b2[f * DT + dbase + dt * 16 + q * 4];

    #pragma unroll
    for (int hh = 0; hh < 2; ++hh) {
        if (hh) SYNC_LDS();                // protect stage[] reuse (LDS-only wait)
        #pragma unroll
        for (int dt = 0; dt < 3; ++dt) {
            f32x4 v = acc[dt][hh] + b2q[dt];
            *(f32x4*)&stage[m][dbase + dt * 16 + q * 4] = v;
        }
        SYNC_LDS();
        // store 16 rows x 768B; every wave instruction = 1KB of full 128B lines
        #pragma unroll
        for (int i = 0; i < 3; ++i) {
            const int idx = i * 256 + tid;       // 0..767 float4 slots
            const int row = idx / 48;
            const int c4  = idx - row * 48;
            f32x4 v = *(const f32x4*)&stage[row][c4 * 4];
            __builtin_nontemporal_store(
                v, (f32x4*)&out[((size_t)(b0 + hh * 16 + row) * N_F + f) * DT + c4 * 4]);
        }
    }
}

extern "C" void kernel_launch(void* const* d_in, const int* in_sizes, int n_in,
                              void* d_out, int out_size, void* d_ws, size_t ws_size,
                              hipStream_t stream) {
    const float* x  = (const float*)d_in[0];
    const float* W1 = (const float*)d_in[1];
    const float* b1 = (const float*)d_in[2];
    const float* W2 = (const float*)d_in[3];
    const float* b2 = (const float*)d_in[4];
    float* out = (float*)d_out;

    const size_t w2f_bytes = (size_t)N_F * DT * DH * sizeof(u16);
    dim3 grid(N_F, N_B / BM);   // f fastest-varying

    if (ws_size >= w2f_bytes) {
        u16* W2F = (u16*)d_ws;
        convert_w2_kernel<<<(N_F * DH * (DT / 4) + 255) / 256, 256, 0, stream>>>(W2, W2F);
        mlp_tok_kernel<true><<<grid, 256, 0, stream>>>(x, W1, b1, W2, b2, W2F, out);
    } else {
        mlp_tok_kernel<false><<<grid, 256, 0, stream>>>(x, W1, b1, W2, b2, nullptr, out);
    }
}